// Round 13
// baseline (648.017 us; speedup 1.0000x reference)
//
#include <hip/hip_runtime.h>
#include <math.h>

// ODE-RNN persistent kernel, round 24: wave-layout fusion, 6 -> 4 barriers.
// R23 post-mortem: VALU 20%, Mfma 16%, ~64% no-issue -> barrier/latency
// bound at ~1.4k cy per phase boundary. Key fact: A-operands use m4=lane&3
// (rows 0-3 replicated over the 16 MFMA rows), so EVERY lane holds
// C_true[r][lane&15] -- lane<16 masks were only store-dedup. So results
// never needed the LDS round-trip to the spread passes:
//   - Phase B fuses dequant+tanh (reads bcx in wave layout, wave-private
//     cols, same-wave ordering -- no barrier); spread1 + S1 + qraw killed.
//     (spread1's ybq write was dead anyway: spread2 always overwrote it.)
//   - feval returns raw G2 accumulators in regs; Euler+quant+yg-store fuse
//     there (y0 re-read from ybuf, wave-private); spread2 + S4b killed.
// Barriers/step: S2, S3, S4, S5. Math op-identical to R23 (absmax ~2e-3).
// Keeps: AGPR Whh (R22 atomic asm load), LDS f-net (R19), int8 (R16).
// Watch: FETCH GBs = register spill of c2/scr -> revert.

#define NWG  256
#define NTHR 1024
#define Tn   100
#define Dn   64
#define Hn   512
#define Fn   50
#define YP   528   // fp16 pitch
#define YQP  544   // i8 pitch
#define XP   80
#define GPp  80
#define GPI  17
#define BXP  516   // bcx pitch (dwords)
#define SB_WHH 2873.682f              // 127 / (1/sqrt(512))
#define QDH (1.0f/(125.0f*SB_WHH))    // dequant: (1/sA)*(1/sB)

typedef __attribute__((ext_vector_type(8))) _Float16 half8;
typedef __attribute__((ext_vector_type(4))) float f32x4;
typedef __attribute__((ext_vector_type(4))) int   i32x4;

__device__ __forceinline__ float my_tanh(float v) {
    float e = __expf(2.0f * v);
    return 1.0f - 2.0f * __builtin_amdgcn_rcpf(e + 1.0f);   // exact 0 at v=0
}
__device__ __forceinline__ float wave_red(float v) {
#pragma unroll
    for (int o = 32; o > 0; o >>= 1) v += __shfl_down(v, o);
    return v;
}
__device__ __forceinline__ signed char q125(float v) {
    return (signed char)(int)rintf(v * 125.0f);
}

// f-net through GEMM2; returns RAW GEMM2 accumulators in c2[] (regs).
// Two internal syncs (S3, S4). Every lane's c2[i][r] = C_true[r][ci_i]
// thanks to the m4=lane&3 row replication.
__device__ __forceinline__ void feval_g2raw(
    const _Float16* arg, const half8* w1b, const half8* w2b,
    float* gp, _Float16* gbf, const float b1v,
    int w, int lane, int tid, f32x4 c2[2])
{
    const int m4 = lane & 3, q = (lane >> 4) & 3;
    const int kh = w >> 2;
    f32x4 acc = {0.f, 0.f, 0.f, 0.f};
    const _Float16* arow = arg + m4 * YP + q * 8;
#pragma unroll
    for (int t = 0; t < 4; ++t) {
        half8 a = *(const half8*)(arow + (kh * 4 + t) * 32);
        acc = __builtin_amdgcn_mfma_f32_16x16x32_f16(a, w1b[t * 64], acc, 0, 0, 0);
    }
    if (lane < 16) {
#pragma unroll
        for (int r = 0; r < 4; ++r)
            gp[(w * 4 + r) * GPI + lane] = acc[r];
    }
    __syncthreads();   // S3
    if (tid < 256) {   // mid layer once: 4 rows x 64 neurons
        const int r = tid >> 6, n = tid & 63;
        const int nt = n >> 4, c = n & 15;
        float s = gp[((0*4 + nt) * 4 + r) * GPI + c]
                + gp[((1*4 + nt) * 4 + r) * GPI + c]
                + gp[((2*4 + nt) * 4 + r) * GPI + c]
                + gp[((3*4 + nt) * 4 + r) * GPI + c];
        float g = (n < Fn) ? my_tanh(s + b1v) : 0.0f;
        gbf[r * GPp + n] = (_Float16)g;
    }
    __syncthreads();   // S4
    half8 af0 = *(const half8*)(gbf + m4 * GPp + q * 8);
    half8 af1 = *(const half8*)(gbf + m4 * GPp + 32 + q * 8);
#pragma unroll
    for (int i = 0; i < 2; ++i) {
        f32x4 c = {0.f, 0.f, 0.f, 0.f};
        c = __builtin_amdgcn_mfma_f32_16x16x32_f16(af0, w2b[(i*2 + 0) * 64], c, 0, 0, 0);
        c = __builtin_amdgcn_mfma_f32_16x16x32_f16(af1, w2b[(i*2 + 1) * 64], c, 0, 0, 0);
        c2[i] = c;
    }
}

extern "C" __global__ void __launch_bounds__(NTHR, 4)
odernn_main(const float* __restrict__ dt, const float* __restrict__ x,
            const float* __restrict__ b_ih, const float* __restrict__ b_hh,
            const float* __restrict__ b1,   const float* __restrict__ b2,
            const float* __restrict__ bl1,  const float* __restrict__ Wmu,
            const float* __restrict__ bmu,
            const _Float16* __restrict__ w1p,  const _Float16* __restrict__ w2p,
            const signed char* __restrict__ whh8, const _Float16* __restrict__ wih,
            const _Float16* __restrict__ wl1p,
            _Float16* __restrict__ yg, float* __restrict__ out, int defer)
{
    __shared__ __align__(16) _Float16 ybuf[4*YP];
    __shared__ __align__(16) signed char ybq[4*YQP];
    __shared__ __align__(16) _Float16 xbuf[4*XP];
    __shared__ __align__(16) _Float16 gbf[4*GPp];
    __shared__ __align__(16) float    gp[64*GPI];
    __shared__ __align__(16) float    bcx[4*BXP];
    __shared__ float sc_row[4], hp[64];
    __shared__ __align__(16) _Float16 w1L[16 * 4 * 64 * 8];   // 64 KB
    __shared__ __align__(16) _Float16 w2L[16 * 4 * 64 * 8];   // 64 KB

    const int tid  = threadIdx.x;
    const int w    = tid >> 6;       // wave 0..15
    const int lane = tid & 63;
    const int m4   = lane & 3, q = (lane >> 4) & 3;
    const int cw   = lane & 15;
    const int row0 = blockIdx.x * 4;

    for (int i = tid; i < 4*YP;  i += NTHR) ybuf[i] = (_Float16)0.0f;
    for (int i = tid; i < 4*YQP; i += NTHR) ybq[i]  = 0;

    // stage loop-invariant f-net fragments into LDS (once; R19-proven)
    {
        half8* w1d = ((half8*)w1L) + (w * 4) * 64 + lane;
        const int kh = w >> 2, nt1 = w & 3;
#pragma unroll
        for (int t = 0; t < 4; ++t) {
            const int kt = kh * 4 + t;
            w1d[t * 64] = ((const half8*)w1p)[(((kt << 2) + nt1) << 6) + lane];
        }
        half8* w2d = ((half8*)w2L) + (w * 4) * 64 + lane;
#pragma unroll
        for (int i = 0; i < 2; ++i) {
            const int nt = w + (i << 4);
            w2d[(i*2 + 0) * 64] = ((const half8*)w2p)[(nt << 6) + lane];
            w2d[(i*2 + 1) * 64] = ((const half8*)w2p)[((32 + nt) << 6) + lane];
        }
    }

    // ---- Whh int8 B-fragments -> AGPRs in ONE atomic asm block (R22-proven)
    i32x4 bq0,  bq1,  bq2,  bq3,  bq4,  bq5,  bq6,  bq7;
    i32x4 bq8,  bq9,  bq10, bq11, bq12, bq13, bq14, bq15;
#define WADDR(kt, ntadd) (whh8 + ((((kt)*32 + w + (ntadd)) << 10) + (lane << 4)))
    asm volatile(
        "global_load_dwordx4 %0, %16, off\n\t"
        "global_load_dwordx4 %1, %17, off\n\t"
        "global_load_dwordx4 %2, %18, off\n\t"
        "global_load_dwordx4 %3, %19, off\n\t"
        "global_load_dwordx4 %4, %20, off\n\t"
        "global_load_dwordx4 %5, %21, off\n\t"
        "global_load_dwordx4 %6, %22, off\n\t"
        "global_load_dwordx4 %7, %23, off\n\t"
        "global_load_dwordx4 %8, %24, off\n\t"
        "global_load_dwordx4 %9, %25, off\n\t"
        "global_load_dwordx4 %10, %26, off\n\t"
        "global_load_dwordx4 %11, %27, off\n\t"
        "global_load_dwordx4 %12, %28, off\n\t"
        "global_load_dwordx4 %13, %29, off\n\t"
        "global_load_dwordx4 %14, %30, off\n\t"
        "global_load_dwordx4 %15, %31, off\n\t"
        "s_waitcnt vmcnt(0)"
        : "=a"(bq0),  "=a"(bq1),  "=a"(bq2),  "=a"(bq3),
          "=a"(bq4),  "=a"(bq5),  "=a"(bq6),  "=a"(bq7),
          "=a"(bq8),  "=a"(bq9),  "=a"(bq10), "=a"(bq11),
          "=a"(bq12), "=a"(bq13), "=a"(bq14), "=a"(bq15)
        : "v"(WADDR(0,0)),  "v"(WADDR(0,16)),
          "v"(WADDR(1,0)),  "v"(WADDR(1,16)),
          "v"(WADDR(2,0)),  "v"(WADDR(2,16)),
          "v"(WADDR(3,0)),  "v"(WADDR(3,16)),
          "v"(WADDR(4,0)),  "v"(WADDR(4,16)),
          "v"(WADDR(5,0)),  "v"(WADDR(5,16)),
          "v"(WADDR(6,0)),  "v"(WADDR(6,16)),
          "v"(WADDR(7,0)),  "v"(WADDR(7,16))
        : "memory");
#undef WADDR

    float bC[2], b2v[2];
    int ci[2];
#pragma unroll
    for (int i = 0; i < 2; ++i) {
        const int n = (w + i*16)*16 + cw;
        bC[i]  = b_ih[n] + b_hh[n];
        b2v[i] = b2[n];
        ci[i]  = n;
    }
    const float b1v = (tid < 256 && (tid & 63) < Fn) ? b1[tid & 63] : 0.0f;
    const float blv = bl1[w*16 + cw];   // fallback head only
    const float wmv = Wmu[w*16 + cw];
    const float bmu0 = bmu[0];

    const half8* w1b = ((const half8*)w1L) + (w * 4) * 64 + lane;
    const half8* w2b = ((const half8*)w2L) + (w * 4) * 64 + lane;

    float xv = 0.f, scn = 0.f;

    // stage x/sc for ts = 0
    if (tid < 256) {
        const int r = tid >> 6, c = tid & 63;
        xbuf[r*XP + c] = (_Float16)x[((size_t)(row0 + r)*Tn + 0)*Dn + c];
    }
    if (tid < 4) {
        const size_t di = ((size_t)(row0 + tid)*Tn + 0)*2;
        sc_row[tid] = (dt[di + 1] - dt[di]) * 0.01f;
    }
    __syncthreads();

#pragma unroll 1
    for (int ts = 0; ts < Tn; ++ts) {
        // ---- Phase A: x@Wih (fp16 MFMA) + bias -> LDS bcx; accX dies here ----
        {
            f32x4 accX0 = {0.f,0.f,0.f,0.f};
            f32x4 accX1 = {0.f,0.f,0.f,0.f};
            const _Float16* xh = xbuf + m4*XP + q*8;
#pragma unroll
            for (int kt = 0; kt < 2; ++kt) {
                half8 ah = *(const half8*)(xh + kt*32);
                half8 bw0 = *(const half8*)(wih + (((kt*32 + w)      << 9) + (lane << 3)));
                half8 bw1 = *(const half8*)(wih + (((kt*32 + w + 16) << 9) + (lane << 3)));
                accX0 = __builtin_amdgcn_mfma_f32_16x16x32_f16(ah, bw0, accX0, 0,0,0);
                accX1 = __builtin_amdgcn_mfma_f32_16x16x32_f16(ah, bw1, accX1, 0,0,0);
            }
            if (lane < 16) {
#pragma unroll
                for (int r = 0; r < 4; ++r) {
                    bcx[r*BXP + ci[0]] = accX0[r] + bC[0];
                    bcx[r*BXP + ci[1]] = accX1[r] + bC[1];
                }
            }
        }
        __builtin_amdgcn_sched_barrier(0);   // pin phase: accX must die here

        // ---- Phase B fused: int8 MFMA (B from AGPRs) + dequant + tanh.
        // bcx cols are wave-private; same-wave produce->consume needs no
        // barrier (lgkmcnt orders it). Every lane holds C_true[r][ci].
        {
            i32x4 accQ0 = {0,0,0,0};
            i32x4 accQ1 = {0,0,0,0};
            const signed char* yq = ybq + m4*YQP + q*16;
            i32x4 aq;
#define QMM(kt, B0, B1, PRE, POST) { \
            aq = *(const i32x4*)(yq + (kt)*64); \
            asm(PRE \
                "v_mfma_i32_16x16x64_i8 %0, %2, %3, %0\n\t" \
                "v_mfma_i32_16x16x64_i8 %1, %2, %4, %1" \
                POST \
                : "+v"(accQ0), "+v"(accQ1) \
                : "v"(aq), "a"(B0), "a"(B1)); }
            QMM(0, bq0,  bq1,  "s_nop 3\n\t", "")
            QMM(1, bq2,  bq3,  "", "")
            QMM(2, bq4,  bq5,  "", "")
            QMM(3, bq6,  bq7,  "", "")
            QMM(4, bq8,  bq9,  "", "")
            QMM(5, bq10, bq11, "", "")
            QMM(6, bq12, bq13, "", "")
            QMM(7, bq14, bq15, "", "\n\ts_nop 7\n\ts_nop 7\n\ts_nop 7")
#undef QMM
#pragma unroll
            for (int r = 0; r < 4; ++r) {
                float p0 = (float)accQ0[r] * QDH + bcx[r*BXP + ci[0]];
                float p1 = (float)accQ1[r] * QDH + bcx[r*BXP + ci[1]];
                float y0a = my_tanh(p0);
                float y0b = my_tanh(p1);
                if (lane < 16) {
                    ybuf[r*YP + ci[0]] = (_Float16)y0a;
                    ybuf[r*YP + ci[1]] = (_Float16)y0b;
                }
            }
        }
        // prefetch x/dt for next step (lands during feval)
        {
            const int tsn = (ts + 1 < Tn) ? ts + 1 : ts;
            if (tid < 256) {
                const int r = tid >> 6, c = tid & 63;
                xv = x[((size_t)(row0 + r)*Tn + tsn)*Dn + c];
            }
            if (tid < 4) {
                const size_t di = ((size_t)(row0 + tid)*Tn + tsn)*2;
                scn = (dt[di + 1] - dt[di]) * 0.01f;
            }
        }
        __syncthreads();   // S2: y0 in ybuf visible to all waves

        // capture row scales (region S2->S3; update happens pre-S5)
        float scr_r[4];
#pragma unroll
        for (int r = 0; r < 4; ++r) scr_r[r] = sc_row[r];

        // ---- ODE f-eval through raw GEMM2 in regs (S3, S4 inside) ----
        f32x4 c2[2];
        feval_g2raw(ybuf, w1b, w2b, gp, gbf, b1v, w, lane, tid, c2);

        // ---- fused Euler + quant + yg store (wave layout, no barrier) ----
#pragma unroll
        for (int i = 0; i < 2; ++i) {
#pragma unroll
            for (int r = 0; r < 4; ++r) {
                float k  = my_tanh(c2[i][r] + b2v[i]) * scr_r[r];
                float yn = (float)ybuf[r*YP + ci[i]] + k;
                if (lane < 16) {
                    ybuf[r*YP + ci[i]] = (_Float16)yn;
                    ybq[r*YQP + ci[i]] = q125(yn);
                    if (defer)
                        yg[((size_t)(row0 + r)*Tn + ts)*512 + ci[i]] = (_Float16)yn;
                }
            }
        }
        if (tid < 256) xbuf[(tid >> 6)*XP + (tid & 63)] = (_Float16)xv;
        if (tid < 4)   sc_row[tid] = scn;
        __syncthreads();   // S5: ynew (ybuf/ybq) + x + sc visible

        if (!defer) {
            // in-loop head (fallback)
            f32x4 aH = {0.f,0.f,0.f,0.f};
            const _Float16* yh = ybuf + m4*YP + q*8;
#pragma unroll 4
            for (int kt = 0; kt < 16; ++kt) {
                half8 ah = *(const half8*)(yh + kt*32);
                half8 b = *(const half8*)(wl1p + ((kt*16 + w) << 9) + (lane << 3));
                aH = __builtin_amdgcn_mfma_f32_16x16x32_f16(ah, b, aH, 0,0,0);
            }
            float pr[4];
#pragma unroll
            for (int r = 0; r < 4; ++r) {
                float p = (lane < 16) ? fmaxf(aH[r] + blv, 0.0f) * wmv : 0.0f;
                pr[r] = wave_red(p);
            }
            if (lane == 0) {
#pragma unroll
                for (int r = 0; r < 4; ++r) hp[w*4 + r] = pr[r];
            }
            __syncthreads();
            if (tid < 4) {
                float s = bmu0;
#pragma unroll
                for (int wv = 0; wv < 16; ++wv) s += hp[wv*4 + tid];
                out[(size_t)(row0 + tid)*Tn + ts] = s;
            }
            __syncthreads();
        }
    }
}

// phase-2 head: out[b,t] = relu(y[b,t]@Wl1^T + bl1)@Wmu^T + bmu
// grid = (B/16)*Tn WGs x 256 threads; wave w covers n in [w*64,(w+1)*64)
extern "C" __global__ void __launch_bounds__(256, 4)
odernn_head(const _Float16* __restrict__ yg, const _Float16* __restrict__ wl1p,
            const float* __restrict__ bl1, const float* __restrict__ Wmu,
            const float* __restrict__ bmu, float* __restrict__ out)
{
    __shared__ float hp[4][16];
    const int tid = threadIdx.x, w = tid >> 6, lane = tid & 63;
    const int q = (lane >> 4) & 3;
    const int b0 = (blockIdx.x / Tn) * 16, ts = blockIdx.x % Tn;

    f32x4 acc[4];
#pragma unroll
    for (int j = 0; j < 4; ++j) acc[j] = (f32x4){0.f,0.f,0.f,0.f};
    const _Float16* ap = yg + ((size_t)(b0 + (lane & 15))*Tn + ts)*512 + q*8;
#pragma unroll 4
    for (int kt = 0; kt < 16; ++kt) {
        half8 a = *(const half8*)(ap + kt*32);
#pragma unroll
        for (int j = 0; j < 4; ++j) {
            half8 b = *(const half8*)(wl1p + ((kt*16 + w*4 + j) << 9) + (lane << 3));
            acc[j] = __builtin_amdgcn_mfma_f32_16x16x32_f16(a, b, acc[j], 0,0,0);
        }
    }
    float pr[4] = {0.f, 0.f, 0.f, 0.f};
#pragma unroll
    for (int j = 0; j < 4; ++j) {
        const int n = (w*4 + j)*16 + (lane & 15);
        const float blv = bl1[n], wmv = Wmu[n];
#pragma unroll
        for (int r = 0; r < 4; ++r)
            pr[r] += fmaxf(acc[j][r] + blv, 0.0f) * wmv;
    }
#pragma unroll
    for (int r = 0; r < 4; ++r)
#pragma unroll
        for (int o = 1; o < 16; o <<= 1) pr[r] += __shfl_xor(pr[r], o);
    if ((lane & 15) == 0) {
        const int g = lane >> 4;
#pragma unroll
        for (int r = 0; r < 4; ++r) hp[w][g*4 + r] = pr[r];
    }
    __syncthreads();
    if (tid < 16)
        out[(size_t)(b0 + tid)*Tn + ts] =
            hp[0][tid] + hp[1][tid] + hp[2][tid] + hp[3][tid] + bmu[0];
}

// pack weights: fp16 MFMA B-fragment order (B[k][n] = W[n][k]) for the
// f-net / wih / wl1; int8 B-fragment order (K=64) for Whh.
extern "C" __global__ void odernn_init(
    const float* __restrict__ W_ih, const float* __restrict__ W_hh,
    const float* __restrict__ W1,   const float* __restrict__ W2,
    const float* __restrict__ Wl1,
    _Float16* w1p, _Float16* w2p, signed char* whh8, _Float16* wih,
    _Float16* wl1p)
{
    const int idx = blockIdx.x * blockDim.x + threadIdx.x;
    const int stride = gridDim.x * blockDim.x;
    // W1: KT=16, NT=4 (N 50->64), K=512
    for (int p = idx; p < 32768; p += stride) {
        int j = p & 7, lane = (p >> 3) & 63, t = p >> 9;
        int nt = t & 3, kt = t >> 2;
        int n = nt*16 + (lane & 15), k = kt*32 + ((lane >> 4) << 3) + j;
        w1p[p] = (_Float16)((n < 50) ? W1[n*512 + k] : 0.f);
    }
    // W2: KT=2 (K 50->64), NT=32, N=512
    for (int p = idx; p < 32768; p += stride) {
        int j = p & 7, lane = (p >> 3) & 63, t = p >> 9;
        int nt = t & 31, kt = t >> 5;
        int n = nt*16 + (lane & 15), k = kt*32 + ((lane >> 4) << 3) + j;
        w2p[p] = (_Float16)((k < 50) ? W2[n*50 + k] : 0.f);
    }
    // Whh int8: KT=8 (K=64 each), NT=32; B frag: 16 bytes/lane,
    // n = nt*16+(lane&15), k = kt*64 + (lane>>4)*16 + j
    for (int p = idx; p < 262144; p += stride) {
        int j = p & 15, lane = (p >> 4) & 63, t = p >> 10;
        int nt = t & 31, kt = t >> 5;
        int n = nt*16 + (lane & 15), k = kt*64 + ((lane >> 4) << 4) + j;
        float v = rintf(W_hh[n*512 + k] * SB_WHH);
        v = fminf(127.0f, fmaxf(-127.0f, v));
        whh8[p] = (signed char)(int)v;
    }
    // Wih: KT=2, NT=32, K=64 (fp16)
    for (int p = idx; p < 32768; p += stride) {
        int j = p & 7, lane = (p >> 3) & 63, t = p >> 9;
        int nt = t & 31, kt = t >> 5;
        int n = nt*16 + (lane & 15), k = kt*32 + ((lane >> 4) << 3) + j;
        wih[p] = (_Float16)W_ih[n*64 + k];
    }
    // Wl1: KT=16, NT=16, N=256, K=512
    for (int p = idx; p < 131072; p += stride) {
        int j = p & 7, lane = (p >> 3) & 63, t = p >> 9;
        int nt = t & 15, kt = t >> 4;
        int n = nt*16 + (lane & 15), k = kt*32 + ((lane >> 4) << 3) + j;
        wl1p[p] = (_Float16)Wl1[n*512 + k];
    }
}

extern "C" void kernel_launch(void* const* d_in, const int* in_sizes, int n_in,
                              void* d_out, int out_size, void* d_ws, size_t ws_size,
                              hipStream_t stream)
{
    (void)in_sizes; (void)n_in; (void)out_size;
    const float* dt   = (const float*)d_in[0];
    const float* x    = (const float*)d_in[1];
    const float* W_ih = (const float*)d_in[2];
    const float* b_ih = (const float*)d_in[3];
    const float* W_hh = (const float*)d_in[4];
    const float* b_hh = (const float*)d_in[5];
    const float* W1   = (const float*)d_in[6];
    const float* b1   = (const float*)d_in[7];
    const float* W2   = (const float*)d_in[8];
    const float* b2   = (const float*)d_in[9];
    const float* Wl1  = (const float*)d_in[10];
    const float* bl1  = (const float*)d_in[11];
    const float* Wmu  = (const float*)d_in[12];
    const float* bmu  = (const float*)d_in[13];
    float* out = (float*)d_out;

    char* ws = (char*)d_ws;
    _Float16*    w1p  = (_Float16*)(ws);             // 64 KB
    _Float16*    w2p  = (_Float16*)(ws + 65536);     // 64 KB
    signed char* whh8 = (signed char*)(ws + 131072); // 256 KB (of 512 KB slot)
    _Float16*    wih  = (_Float16*)(ws + 655360);    // 64 KB
    _Float16*    wl1p = (_Float16*)(ws + 720896);    // 256 KB
    _Float16*    yg   = (_Float16*)(ws + 1048576);   // 105 MB (if available)

    const size_t need = 1048576 + (size_t)1024 * Tn * 512 * sizeof(_Float16);
    const int defer = (ws_size >= need) ? 1 : 0;

    odernn_init<<<256, 256, 0, stream>>>(W_ih, W_hh, W1, W2, Wl1,
                                         w1p, w2p, whh8, wih, wl1p);
    odernn_main<<<NWG, NTHR, 0, stream>>>(dt, x, b_ih, b_hh, b1, b2, bl1, Wmu, bmu,
                                          w1p, w2p, whh8, wih, wl1p,
                                          yg, out, defer);
    if (defer)
        odernn_head<<<(1024/16)*Tn, 256, 0, stream>>>(yg, wl1p, bl1, Wmu, bmu, out);
}

// Round 14
// 550.951 us; speedup vs baseline: 1.1762x; 1.1762x over previous
//
#include <hip/hip_runtime.h>
#include <math.h>

// ODE-RNN persistent kernel, round 25: diagonal lane->row assignment.
// R24 post-mortem: wave-layout fusion removed 2 barriers but every lane
// redundantly computed all 4 rows (4x q-group duplication + scalar LDS
// reads): VALUBusy 20->42%, net -32us. R25 exploits the replication the
// other way: lane (q,cw) holds C_true[r][col] for ALL r in regs; assign
// r=q=lane>>4 -> 64 lanes cover the wave's 128 distinct values with
// 2/lane, zero redundancy, zero LDS staging, zero barriers. Extraction
// of element q = hand-written 3-cndmask tree (no scratch).
//   - Phase A: no bcx LDS; ax = accX[q]+bC (2 scalars live -> no spill).
//   - Phase B: 2 tanh/lane; y0 kept in regs (ya, yb) for Euler.
//   - G1 partials: 1 store/lane (was 4 stores in 1/4 lanes).
//   - Euler: 2 tanh/lane + fused ybuf/ybq/yg stores.
// Barriers/step: S2,S3,S4,S5. Math op-identical to R23 -> absmax ~2e-3.
// Keeps: AGPR Whh (R22 atomic asm), LDS f-net (R19), int8 (R16).
// Watch: FETCH GBs = accX/c2 spill -> revert; dur >=470 = boundary model
// wrong -> ablation template next.

#define NWG  256
#define NTHR 1024
#define Tn   100
#define Dn   64
#define Hn   512
#define Fn   50
#define YP   528   // fp16 pitch
#define YQP  544   // i8 pitch
#define XP   80
#define GPp  80
#define GPI  17
#define SB_WHH 2873.682f              // 127 / (1/sqrt(512))
#define QDH (1.0f/(125.0f*SB_WHH))    // dequant: (1/sA)*(1/sB)

typedef __attribute__((ext_vector_type(8))) _Float16 half8;
typedef __attribute__((ext_vector_type(4))) float f32x4;
typedef __attribute__((ext_vector_type(4))) int   i32x4;

__device__ __forceinline__ float my_tanh(float v) {
    float e = __expf(2.0f * v);
    return 1.0f - 2.0f * __builtin_amdgcn_rcpf(e + 1.0f);   // exact 0 at v=0
}
__device__ __forceinline__ float wave_red(float v) {
#pragma unroll
    for (int o = 32; o > 0; o >>= 1) v += __shfl_down(v, o);
    return v;
}
__device__ __forceinline__ signed char q125(float v) {
    return (signed char)(int)rintf(v * 125.0f);
}
// constant-index select trees (per-lane q; no scratch, pure v_cndmask)
__device__ __forceinline__ float selq4(f32x4 v, int qq) {
    float a = (qq & 1) ? v[1] : v[0];
    float b = (qq & 1) ? v[3] : v[2];
    return (qq & 2) ? b : a;
}
__device__ __forceinline__ float selq4i(i32x4 v, int qq) {
    int a = (qq & 1) ? v[1] : v[0];
    int b = (qq & 1) ? v[3] : v[2];
    return (float)((qq & 2) ? b : a);
}

// f-net through GEMM2; returns RAW GEMM2 accumulators in c2[] (regs).
// Two internal syncs (S3, S4). gp partial store uses the diagonal
// assignment: all 64 lanes store one value (r=q).
__device__ __forceinline__ void feval_g2raw(
    const _Float16* arg, const half8* w1b, const half8* w2b,
    float* gp, _Float16* gbf, const float b1v,
    int w, int lane, int tid, int qq, f32x4 c2[2])
{
    const int m4 = lane & 3, cw = lane & 15;
    const int kh = w >> 2;
    f32x4 acc = {0.f, 0.f, 0.f, 0.f};
    const _Float16* arow = arg + m4 * YP + qq * 8;
#pragma unroll
    for (int t = 0; t < 4; ++t) {
        half8 a = *(const half8*)(arow + (kh * 4 + t) * 32);
        acc = __builtin_amdgcn_mfma_f32_16x16x32_f16(a, w1b[t * 64], acc, 0, 0, 0);
    }
    gp[(w * 4 + qq) * GPI + cw] = selq4(acc, qq);
    __syncthreads();   // S3
    if (tid < 256) {   // mid layer once: 4 rows x 64 neurons (true K-reduce)
        const int r = tid >> 6, n = tid & 63;
        const int nt = n >> 4, c = n & 15;
        float s = gp[((0*4 + nt) * 4 + r) * GPI + c]
                + gp[((1*4 + nt) * 4 + r) * GPI + c]
                + gp[((2*4 + nt) * 4 + r) * GPI + c]
                + gp[((3*4 + nt) * 4 + r) * GPI + c];
        float g = (n < Fn) ? my_tanh(s + b1v) : 0.0f;
        gbf[r * GPp + n] = (_Float16)g;
    }
    __syncthreads();   // S4
    half8 af0 = *(const half8*)(gbf + m4 * GPp + qq * 8);
    half8 af1 = *(const half8*)(gbf + m4 * GPp + 32 + qq * 8);
#pragma unroll
    for (int i = 0; i < 2; ++i) {
        f32x4 c = {0.f, 0.f, 0.f, 0.f};
        c = __builtin_amdgcn_mfma_f32_16x16x32_f16(af0, w2b[(i*2 + 0) * 64], c, 0, 0, 0);
        c = __builtin_amdgcn_mfma_f32_16x16x32_f16(af1, w2b[(i*2 + 1) * 64], c, 0, 0, 0);
        c2[i] = c;
    }
}

extern "C" __global__ void __launch_bounds__(NTHR, 4)
odernn_main(const float* __restrict__ dt, const float* __restrict__ x,
            const float* __restrict__ b_ih, const float* __restrict__ b_hh,
            const float* __restrict__ b1,   const float* __restrict__ b2,
            const float* __restrict__ bl1,  const float* __restrict__ Wmu,
            const float* __restrict__ bmu,
            const _Float16* __restrict__ w1p,  const _Float16* __restrict__ w2p,
            const signed char* __restrict__ whh8, const _Float16* __restrict__ wih,
            const _Float16* __restrict__ wl1p,
            _Float16* __restrict__ yg, float* __restrict__ out, int defer)
{
    __shared__ __align__(16) _Float16 ybuf[4*YP];
    __shared__ __align__(16) signed char ybq[4*YQP];
    __shared__ __align__(16) _Float16 xbuf[4*XP];
    __shared__ __align__(16) _Float16 gbf[4*GPp];
    __shared__ __align__(16) float    gp[64*GPI];
    __shared__ float sc_row[4], hp[64];
    __shared__ __align__(16) _Float16 w1L[16 * 4 * 64 * 8];   // 64 KB
    __shared__ __align__(16) _Float16 w2L[16 * 4 * 64 * 8];   // 64 KB

    const int tid  = threadIdx.x;
    const int w    = tid >> 6;       // wave 0..15
    const int lane = tid & 63;
    const int m4   = lane & 3, q = (lane >> 4) & 3;
    const int cw   = lane & 15;
    const int row0 = blockIdx.x * 4;

    for (int i = tid; i < 4*YP;  i += NTHR) ybuf[i] = (_Float16)0.0f;
    for (int i = tid; i < 4*YQP; i += NTHR) ybq[i]  = 0;

    // stage loop-invariant f-net fragments into LDS (once; R19-proven)
    {
        half8* w1d = ((half8*)w1L) + (w * 4) * 64 + lane;
        const int kh = w >> 2, nt1 = w & 3;
#pragma unroll
        for (int t = 0; t < 4; ++t) {
            const int kt = kh * 4 + t;
            w1d[t * 64] = ((const half8*)w1p)[(((kt << 2) + nt1) << 6) + lane];
        }
        half8* w2d = ((half8*)w2L) + (w * 4) * 64 + lane;
#pragma unroll
        for (int i = 0; i < 2; ++i) {
            const int nt = w + (i << 4);
            w2d[(i*2 + 0) * 64] = ((const half8*)w2p)[(nt << 6) + lane];
            w2d[(i*2 + 1) * 64] = ((const half8*)w2p)[((32 + nt) << 6) + lane];
        }
    }

    // ---- Whh int8 B-fragments -> AGPRs in ONE atomic asm block (R22-proven)
    i32x4 bq0,  bq1,  bq2,  bq3,  bq4,  bq5,  bq6,  bq7;
    i32x4 bq8,  bq9,  bq10, bq11, bq12, bq13, bq14, bq15;
#define WADDR(kt, ntadd) (whh8 + ((((kt)*32 + w + (ntadd)) << 10) + (lane << 4)))
    asm volatile(
        "global_load_dwordx4 %0, %16, off\n\t"
        "global_load_dwordx4 %1, %17, off\n\t"
        "global_load_dwordx4 %2, %18, off\n\t"
        "global_load_dwordx4 %3, %19, off\n\t"
        "global_load_dwordx4 %4, %20, off\n\t"
        "global_load_dwordx4 %5, %21, off\n\t"
        "global_load_dwordx4 %6, %22, off\n\t"
        "global_load_dwordx4 %7, %23, off\n\t"
        "global_load_dwordx4 %8, %24, off\n\t"
        "global_load_dwordx4 %9, %25, off\n\t"
        "global_load_dwordx4 %10, %26, off\n\t"
        "global_load_dwordx4 %11, %27, off\n\t"
        "global_load_dwordx4 %12, %28, off\n\t"
        "global_load_dwordx4 %13, %29, off\n\t"
        "global_load_dwordx4 %14, %30, off\n\t"
        "global_load_dwordx4 %15, %31, off\n\t"
        "s_waitcnt vmcnt(0)"
        : "=a"(bq0),  "=a"(bq1),  "=a"(bq2),  "=a"(bq3),
          "=a"(bq4),  "=a"(bq5),  "=a"(bq6),  "=a"(bq7),
          "=a"(bq8),  "=a"(bq9),  "=a"(bq10), "=a"(bq11),
          "=a"(bq12), "=a"(bq13), "=a"(bq14), "=a"(bq15)
        : "v"(WADDR(0,0)),  "v"(WADDR(0,16)),
          "v"(WADDR(1,0)),  "v"(WADDR(1,16)),
          "v"(WADDR(2,0)),  "v"(WADDR(2,16)),
          "v"(WADDR(3,0)),  "v"(WADDR(3,16)),
          "v"(WADDR(4,0)),  "v"(WADDR(4,16)),
          "v"(WADDR(5,0)),  "v"(WADDR(5,16)),
          "v"(WADDR(6,0)),  "v"(WADDR(6,16)),
          "v"(WADDR(7,0)),  "v"(WADDR(7,16))
        : "memory");
#undef WADDR

    float bC[2], b2v[2];
    int ci[2];
#pragma unroll
    for (int i = 0; i < 2; ++i) {
        const int n = (w + i*16)*16 + cw;
        bC[i]  = b_ih[n] + b_hh[n];
        b2v[i] = b2[n];
        ci[i]  = n;
    }
    const float b1v = (tid < 256 && (tid & 63) < Fn) ? b1[tid & 63] : 0.0f;
    const float blv = bl1[w*16 + cw];   // fallback head only
    const float wmv = Wmu[w*16 + cw];
    const float bmu0 = bmu[0];

    const half8* w1b = ((const half8*)w1L) + (w * 4) * 64 + lane;
    const half8* w2b = ((const half8*)w2L) + (w * 4) * 64 + lane;

    float xv = 0.f, scn = 0.f;

    // stage x/sc for ts = 0
    if (tid < 256) {
        const int r = tid >> 6, c = tid & 63;
        xbuf[r*XP + c] = (_Float16)x[((size_t)(row0 + r)*Tn + 0)*Dn + c];
    }
    if (tid < 4) {
        const size_t di = ((size_t)(row0 + tid)*Tn + 0)*2;
        sc_row[tid] = (dt[di + 1] - dt[di]) * 0.01f;
    }
    __syncthreads();

#pragma unroll 1
    for (int ts = 0; ts < Tn; ++ts) {
        // ---- Phase A: x@Wih MFMA; extract row q -> 2 scalars (no LDS) ----
        float ax0, ax1;
        {
            f32x4 accX0 = {0.f,0.f,0.f,0.f};
            f32x4 accX1 = {0.f,0.f,0.f,0.f};
            const _Float16* xh = xbuf + m4*XP + q*8;
#pragma unroll
            for (int kt = 0; kt < 2; ++kt) {
                half8 ah = *(const half8*)(xh + kt*32);
                half8 bw0 = *(const half8*)(wih + (((kt*32 + w)      << 9) + (lane << 3)));
                half8 bw1 = *(const half8*)(wih + (((kt*32 + w + 16) << 9) + (lane << 3)));
                accX0 = __builtin_amdgcn_mfma_f32_16x16x32_f16(ah, bw0, accX0, 0,0,0);
                accX1 = __builtin_amdgcn_mfma_f32_16x16x32_f16(ah, bw1, accX1, 0,0,0);
            }
            ax0 = selq4(accX0, q) + bC[0];
            ax1 = selq4(accX1, q) + bC[1];
        }

        // ---- Phase B: int8 MFMA (B from AGPRs) + diagonal dequant+tanh ----
        float ya, yb;
        {
            i32x4 accQ0 = {0,0,0,0};
            i32x4 accQ1 = {0,0,0,0};
            const signed char* yq = ybq + m4*YQP + q*16;
            i32x4 aq;
#define QMM(kt, B0, B1, PRE, POST) { \
            aq = *(const i32x4*)(yq + (kt)*64); \
            asm(PRE \
                "v_mfma_i32_16x16x64_i8 %0, %2, %3, %0\n\t" \
                "v_mfma_i32_16x16x64_i8 %1, %2, %4, %1" \
                POST \
                : "+v"(accQ0), "+v"(accQ1) \
                : "v"(aq), "a"(B0), "a"(B1)); }
            QMM(0, bq0,  bq1,  "s_nop 3\n\t", "")
            QMM(1, bq2,  bq3,  "", "")
            QMM(2, bq4,  bq5,  "", "")
            QMM(3, bq6,  bq7,  "", "")
            QMM(4, bq8,  bq9,  "", "")
            QMM(5, bq10, bq11, "", "")
            QMM(6, bq12, bq13, "", "")
            QMM(7, bq14, bq15, "", "\n\ts_nop 7\n\ts_nop 7\n\ts_nop 7")
#undef QMM
            ya = my_tanh(selq4i(accQ0, q) * QDH + ax0);
            yb = my_tanh(selq4i(accQ1, q) * QDH + ax1);
            ybuf[q*YP + ci[0]] = (_Float16)ya;
            ybuf[q*YP + ci[1]] = (_Float16)yb;
        }
        // prefetch x/dt for next step (lands during feval)
        {
            const int tsn = (ts + 1 < Tn) ? ts + 1 : ts;
            if (tid < 256) {
                const int r = tid >> 6, c = tid & 63;
                xv = x[((size_t)(row0 + r)*Tn + tsn)*Dn + c];
            }
            if (tid < 4) {
                const size_t di = ((size_t)(row0 + tid)*Tn + tsn)*2;
                scn = (dt[di + 1] - dt[di]) * 0.01f;
            }
        }
        __syncthreads();   // S2: y0 in ybuf visible to all waves

        // capture row scale for this lane's row (region S2->S3; update pre-S5)
        const float scq = sc_row[q];

        // ---- ODE f-eval through raw GEMM2 in regs (S3, S4 inside) ----
        f32x4 c2[2];
        feval_g2raw(ybuf, w1b, w2b, gp, gbf, b1v, w, lane, tid, q, c2);

        // ---- fused Euler + quant + yg store (diagonal, no barrier) ----
        {
            float k0 = my_tanh(selq4(c2[0], q) + b2v[0]) * scq;
            float k1 = my_tanh(selq4(c2[1], q) + b2v[1]) * scq;
            float yn0 = ya + k0;
            float yn1 = yb + k1;
            ybuf[q*YP + ci[0]] = (_Float16)yn0;
            ybuf[q*YP + ci[1]] = (_Float16)yn1;
            ybq[q*YQP + ci[0]] = q125(yn0);
            ybq[q*YQP + ci[1]] = q125(yn1);
            if (defer) {
                yg[((size_t)(row0 + q)*Tn + ts)*512 + ci[0]] = (_Float16)yn0;
                yg[((size_t)(row0 + q)*Tn + ts)*512 + ci[1]] = (_Float16)yn1;
            }
        }
        if (tid < 256) xbuf[(tid >> 6)*XP + (tid & 63)] = (_Float16)xv;
        if (tid < 4)   sc_row[tid] = scn;
        __syncthreads();   // S5: ynew (ybuf/ybq) + x + sc visible

        if (!defer) {
            // in-loop head (fallback)
            f32x4 aH = {0.f,0.f,0.f,0.f};
            const _Float16* yh = ybuf + m4*YP + q*8;
#pragma unroll 4
            for (int kt = 0; kt < 16; ++kt) {
                half8 ah = *(const half8*)(yh + kt*32);
                half8 b = *(const half8*)(wl1p + ((kt*16 + w) << 9) + (lane << 3));
                aH = __builtin_amdgcn_mfma_f32_16x16x32_f16(ah, b, aH, 0,0,0);
            }
            float pr[4];
#pragma unroll
            for (int r = 0; r < 4; ++r) {
                float p = (lane < 16) ? fmaxf(aH[r] + blv, 0.0f) * wmv : 0.0f;
                pr[r] = wave_red(p);
            }
            if (lane == 0) {
#pragma unroll
                for (int r = 0; r < 4; ++r) hp[w*4 + r] = pr[r];
            }
            __syncthreads();
            if (tid < 4) {
                float s = bmu0;
#pragma unroll
                for (int wv = 0; wv < 16; ++wv) s += hp[wv*4 + tid];
                out[(size_t)(row0 + tid)*Tn + ts] = s;
            }
            __syncthreads();
        }
    }
}

// phase-2 head: out[b,t] = relu(y[b,t]@Wl1^T + bl1)@Wmu^T + bmu
// grid = (B/16)*Tn WGs x 256 threads; wave w covers n in [w*64,(w+1)*64)
extern "C" __global__ void __launch_bounds__(256, 4)
odernn_head(const _Float16* __restrict__ yg, const _Float16* __restrict__ wl1p,
            const float* __restrict__ bl1, const float* __restrict__ Wmu,
            const float* __restrict__ bmu, float* __restrict__ out)
{
    __shared__ float hp[4][16];
    const int tid = threadIdx.x, w = tid >> 6, lane = tid & 63;
    const int q = (lane >> 4) & 3;
    const int b0 = (blockIdx.x / Tn) * 16, ts = blockIdx.x % Tn;

    f32x4 acc[4];
#pragma unroll
    for (int j = 0; j < 4; ++j) acc[j] = (f32x4){0.f,0.f,0.f,0.f};
    const _Float16* ap = yg + ((size_t)(b0 + (lane & 15))*Tn + ts)*512 + q*8;
#pragma unroll 4
    for (int kt = 0; kt < 16; ++kt) {
        half8 a = *(const half8*)(ap + kt*32);
#pragma unroll
        for (int j = 0; j < 4; ++j) {
            half8 b = *(const half8*)(wl1p + ((kt*16 + w*4 + j) << 9) + (lane << 3));
            acc[j] = __builtin_amdgcn_mfma_f32_16x16x32_f16(a, b, acc[j], 0,0,0);
        }
    }
    float pr[4] = {0.f, 0.f, 0.f, 0.f};
#pragma unroll
    for (int j = 0; j < 4; ++j) {
        const int n = (w*4 + j)*16 + (lane & 15);
        const float blv = bl1[n], wmv = Wmu[n];
#pragma unroll
        for (int r = 0; r < 4; ++r)
            pr[r] += fmaxf(acc[j][r] + blv, 0.0f) * wmv;
    }
#pragma unroll
    for (int r = 0; r < 4; ++r)
#pragma unroll
        for (int o = 1; o < 16; o <<= 1) pr[r] += __shfl_xor(pr[r], o);
    if ((lane & 15) == 0) {
        const int g = lane >> 4;
#pragma unroll
        for (int r = 0; r < 4; ++r) hp[w][g*4 + r] = pr[r];
    }
    __syncthreads();
    if (tid < 16)
        out[(size_t)(b0 + tid)*Tn + ts] =
            hp[0][tid] + hp[1][tid] + hp[2][tid] + hp[3][tid] + bmu[0];
}

// pack weights: fp16 MFMA B-fragment order (B[k][n] = W[n][k]) for the
// f-net / wih / wl1; int8 B-fragment order (K=64) for Whh.
extern "C" __global__ void odernn_init(
    const float* __restrict__ W_ih, const float* __restrict__ W_hh,
    const float* __restrict__ W1,   const float* __restrict__ W2,
    const float* __restrict__ Wl1,
    _Float16* w1p, _Float16* w2p, signed char* whh8, _Float16* wih,
    _Float16* wl1p)
{
    const int idx = blockIdx.x * blockDim.x + threadIdx.x;
    const int stride = gridDim.x * blockDim.x;
    // W1: KT=16, NT=4 (N 50->64), K=512
    for (int p = idx; p < 32768; p += stride) {
        int j = p & 7, lane = (p >> 3) & 63, t = p >> 9;
        int nt = t & 3, kt = t >> 2;
        int n = nt*16 + (lane & 15), k = kt*32 + ((lane >> 4) << 3) + j;
        w1p[p] = (_Float16)((n < 50) ? W1[n*512 + k] : 0.f);
    }
    // W2: KT=2 (K 50->64), NT=32, N=512
    for (int p = idx; p < 32768; p += stride) {
        int j = p & 7, lane = (p >> 3) & 63, t = p >> 9;
        int nt = t & 31, kt = t >> 5;
        int n = nt*16 + (lane & 15), k = kt*32 + ((lane >> 4) << 3) + j;
        w2p[p] = (_Float16)((k < 50) ? W2[n*50 + k] : 0.f);
    }
    // Whh int8: KT=8 (K=64 each), NT=32; B frag: 16 bytes/lane,
    // n = nt*16+(lane&15), k = kt*64 + (lane>>4)*16 + j
    for (int p = idx; p < 262144; p += stride) {
        int j = p & 15, lane = (p >> 4) & 63, t = p >> 10;
        int nt = t & 31, kt = t >> 5;
        int n = nt*16 + (lane & 15), k = kt*64 + ((lane >> 4) << 4) + j;
        float v = rintf(W_hh[n*512 + k] * SB_WHH);
        v = fminf(127.0f, fmaxf(-127.0f, v));
        whh8[p] = (signed char)(int)v;
    }
    // Wih: KT=2, NT=32, K=64 (fp16)
    for (int p = idx; p < 32768; p += stride) {
        int j = p & 7, lane = (p >> 3) & 63, t = p >> 9;
        int nt = t & 31, kt = t >> 5;
        int n = nt*16 + (lane & 15), k = kt*32 + ((lane >> 4) << 3) + j;
        wih[p] = (_Float16)W_ih[n*64 + k];
    }
    // Wl1: KT=16, NT=16, N=256, K=512
    for (int p = idx; p < 131072; p += stride) {
        int j = p & 7, lane = (p >> 3) & 63, t = p >> 9;
        int nt = t & 15, kt = t >> 4;
        int n = nt*16 + (lane & 15), k = kt*32 + ((lane >> 4) << 3) + j;
        wl1p[p] = (_Float16)Wl1[n*512 + k];
    }
}

extern "C" void kernel_launch(void* const* d_in, const int* in_sizes, int n_in,
                              void* d_out, int out_size, void* d_ws, size_t ws_size,
                              hipStream_t stream)
{
    (void)in_sizes; (void)n_in; (void)out_size;
    const float* dt   = (const float*)d_in[0];
    const float* x    = (const float*)d_in[1];
    const float* W_ih = (const float*)d_in[2];
    const float* b_ih = (const float*)d_in[3];
    const float* W_hh = (const float*)d_in[4];
    const float* b_hh = (const float*)d_in[5];
    const float* W1   = (const float*)d_in[6];
    const float* b1   = (const float*)d_in[7];
    const float* W2   = (const float*)d_in[8];
    const float* b2   = (const float*)d_in[9];
    const float* Wl1  = (const float*)d_in[10];
    const float* bl1  = (const float*)d_in[11];
    const float* Wmu  = (const float*)d_in[12];
    const float* bmu  = (const float*)d_in[13];
    float* out = (float*)d_out;

    char* ws = (char*)d_ws;
    _Float16*    w1p  = (_Float16*)(ws);             // 64 KB
    _Float16*    w2p  = (_Float16*)(ws + 65536);     // 64 KB
    signed char* whh8 = (signed char*)(ws + 131072); // 256 KB (of 512 KB slot)
    _Float16*    wih  = (_Float16*)(ws + 655360);    // 64 KB
    _Float16*    wl1p = (_Float16*)(ws + 720896);    // 256 KB
    _Float16*    yg   = (_Float16*)(ws + 1048576);   // 105 MB (if available)

    const size_t need = 1048576 + (size_t)1024 * Tn * 512 * sizeof(_Float16);
    const int defer = (ws_size >= need) ? 1 : 0;

    odernn_init<<<256, 256, 0, stream>>>(W_ih, W_hh, W1, W2, Wl1,
                                         w1p, w2p, whh8, wih, wl1p);
    odernn_main<<<NWG, NTHR, 0, stream>>>(dt, x, b_ih, b_hh, b1, b2, bl1, Wmu, bmu,
                                          w1p, w2p, whh8, wih, wl1p,
                                          yg, out, defer);
    if (defer)
        odernn_head<<<(1024/16)*Tn, 256, 0, stream>>>(yg, wl1p, bl1, Wmu, bmu, out);
}